// Round 5
// baseline (118.301 us; speedup 1.0000x reference)
//
#include <hip/hip_runtime.h>
#include <hip/hip_bf16.h>

typedef __attribute__((ext_vector_type(8))) short bf16x8;
typedef __attribute__((ext_vector_type(4))) float f32x4;

#define QSCALE 0.1803368801111244f   // 0.125 * log2(e): softmax in exp2 domain

static __device__ inline short f2bf(float f) {
    union { float f; unsigned u; } x; x.f = f;
    unsigned r = x.u + 0x7FFF + ((x.u >> 16) & 1);   // RNE
    return (short)(r >> 16);
}

static __device__ inline void gload_lds16(const void* g, void* l) {
    __builtin_amdgcn_global_load_lds(
        (const __attribute__((address_space(1))) unsigned*)g,
        (__attribute__((address_space(3))) unsigned*)l, 16, 0, 0);
}

// ---------------------------------------------------------------------------
// Kernel 0: prep.
//   blocks [0,1024):     hidden_states f32 -> bf16            (Hb [4096][1024])
//   blocks [1024,1792):  c_attn_w [1024][3072] -> bf16 T      (W1t [3072][1024])
//   blocks [1792,2048):  c_proj_w [1024][1024] -> bf16 T      (W2t [1024][1024])
// ---------------------------------------------------------------------------
__global__ __launch_bounds__(256) void prep(
    const float* __restrict__ hs, const float* __restrict__ w1,
    const float* __restrict__ w2,
    short* __restrict__ Hb, short* __restrict__ W1t, short* __restrict__ W2t)
{
    __shared__ short Ts[64][72];
    const int t = threadIdx.x;
    const int blk = blockIdx.x;

    if (blk < 1024) {
        #pragma unroll
        for (int it = 0; it < 4; ++it) {
            long i4 = (long)blk * 1024 + it * 256 + t;
            float4 v = reinterpret_cast<const float4*>(hs)[i4];
            short4 s4;
            s4.x = f2bf(v.x); s4.y = f2bf(v.y); s4.z = f2bf(v.z); s4.w = f2bf(v.w);
            reinterpret_cast<short4*>(Hb)[i4] = s4;
        }
        return;
    }

    const float* W; short* Wt; int NC, tx, ty;
    if (blk < 1792) { int id = blk - 1024; W = w1; Wt = W1t; NC = 3072; tx = id % 48; ty = id / 48; }
    else            { int id = blk - 1792; W = w2; Wt = W2t; NC = 1024; tx = id % 16; ty = id / 16; }
    const int r0 = ty * 64;
    const int c0 = tx * 64;

    #pragma unroll
    for (int it = 0; it < 4; ++it) {
        int slot = t + it * 256;
        int row = slot >> 4, c4 = (slot & 15) << 2;
        float4 v = *reinterpret_cast<const float4*>(&W[(long)(r0 + row) * NC + c0 + c4]);
        Ts[c4 + 0][row] = f2bf(v.x);
        Ts[c4 + 1][row] = f2bf(v.y);
        Ts[c4 + 2][row] = f2bf(v.z);
        Ts[c4 + 3][row] = f2bf(v.w);
    }
    __syncthreads();
    #pragma unroll
    for (int it = 0; it < 2; ++it) {
        int slot = t + it * 256;
        int orow = slot >> 3, ok8 = (slot & 7) << 3;
        *reinterpret_cast<bf16x8*>(&Wt[(long)(c0 + orow) * 1024 + r0 + ok8]) =
            *reinterpret_cast<const bf16x8*>(&Ts[orow][ok8]);
    }
}

// ---------------------------------------------------------------------------
// Kernel 1: fused QKV projection (m97 structure), one launch, 768 blocks:
//   swz < 512:  QK  — C[4096,2048] = Hb @ W1t[0:2048]^T + b, scatter Q/K
//   swz >= 512: V^T — Vt[1024,4096] = W1t[2048:] @ Hb^T + b (pre-transposed V)
// XCD-bijective block swizzle (768 % 8 == 0).
// ---------------------------------------------------------------------------
__global__ __launch_bounds__(256) void qkv_all(
    const short* __restrict__ Hb,     // [4096][1024] bf16
    const short* __restrict__ W1t,    // [3072][1024] bf16 (N-major)
    const float* __restrict__ bias,   // [3072]
    short* __restrict__ Qw, short* __restrict__ Kw, short* __restrict__ Vt)
{
    __shared__ short As[128 * 64];
    __shared__ short Bs[128 * 64];

    const int t  = threadIdx.x;
    const int w  = t >> 6, l = t & 63;
    const int g  = l >> 4, lr = l & 15;
    const int wm = (w >> 1) * 64, wn = (w & 1) * 64;
    const int srow = l >> 3, sc = (l & 7) << 3;

    const int swz = (blockIdx.x & 7) * 96 + (blockIdx.x >> 3);  // XCD-bijective
    const bool isQK = (swz < 512);
    const short *Ap, *Btp;
    int m0, n0;
    if (isQK) {
        m0 = (swz & 31) * 128;          // token tile
        n0 = (swz >> 5) * 128;          // qk-col tile
        Ap = Hb; Btp = W1t;
    } else {
        int id = swz - 512;
        m0 = (id & 7) * 128;            // v-dim tile
        n0 = (id >> 3) * 128;           // token tile
        Ap = W1t + 2097152L; Btp = Hb;
    }

    f32x4 acc[4][4] = {};

    for (int k0 = 0; k0 < 1024; k0 += 64) {
        #pragma unroll
        for (int it = 0; it < 4; ++it) {
            const int seg = w * 4 + it;
            const int row = seg * 8 + srow;
            gload_lds16(&Ap [(long)(m0 + row) * 1024 + k0 + sc], &As[seg * 512]);
            gload_lds16(&Btp[(long)(n0 + row) * 1024 + k0 + sc], &Bs[seg * 512]);
        }
        __syncthreads();
        #pragma unroll
        for (int kk = 0; kk < 64; kk += 32) {
            bf16x8 af[4], bfv[4];
            #pragma unroll
            for (int mi = 0; mi < 4; ++mi)
                af[mi] = *reinterpret_cast<const bf16x8*>(&As[(wm + mi * 16 + lr) * 64 + kk + g * 8]);
            #pragma unroll
            for (int ni = 0; ni < 4; ++ni)
                bfv[ni] = *reinterpret_cast<const bf16x8*>(&Bs[(wn + ni * 16 + lr) * 64 + kk + g * 8]);
            #pragma unroll
            for (int mi = 0; mi < 4; ++mi)
                #pragma unroll
                for (int ni = 0; ni < 4; ++ni)
                    acc[mi][ni] = __builtin_amdgcn_mfma_f32_16x16x32_bf16(
                        af[mi], bfv[ni], acc[mi][ni], 0, 0, 0);
        }
        __syncthreads();
    }

    if (isQK) {
        #pragma unroll
        for (int mi = 0; mi < 4; ++mi) {
            #pragma unroll
            for (int ni = 0; ni < 4; ++ni) {
                int n = n0 + wn + ni * 16 + lr;
                float bv = bias[n];
                int sel = n >> 10, d = n & 1023;
                int h = d >> 6, hi = d & 63;
                short* dst = sel ? Kw : Qw;
                float sc_ = sel ? 1.0f : QSCALE;
                #pragma unroll
                for (int r = 0; r < 4; ++r) {
                    int m = m0 + wm + mi * 16 + g * 4 + r;
                    int b = m >> 10, s = m & 1023;
                    dst[(((b * 16 + h) * 1024 + s) * 64 + hi)] = f2bf((acc[mi][ni][r] + bv) * sc_);
                }
            }
        }
    } else {
        #pragma unroll
        for (int mi = 0; mi < 4; ++mi)
            #pragma unroll
            for (int r = 0; r < 4; ++r) {
                int m = m0 + wm + mi * 16 + g * 4 + r;      // v-dim
                float bv = bias[2048 + m];
                #pragma unroll
                for (int ni = 0; ni < 4; ++ni) {
                    int n = n0 + wn + ni * 16 + lr;          // token
                    int b = n >> 10, s = n & 1023;
                    Vt[(long)b * 1048576 + (long)m * 1024 + s] = f2bf(acc[mi][ni][r] + bv);
                }
            }
    }
}

// ---------------------------------------------------------------------------
// Kernel 2: flash attention v3.  1024 blocks (one q-tile each), longest-first.
// Exp2-direct softmax, deferred cross-lane sum, both-sides XOR swizzle,
// 2-phase double buffer, setprio around MFMA clusters (T5).
// ---------------------------------------------------------------------------
__global__ __launch_bounds__(256) void attn(
    const short* __restrict__ Qw, const short* __restrict__ Kw,
    const short* __restrict__ Vt, short* __restrict__ Aw)
{
    __shared__ short Kb[2][4096];
    __shared__ short Vb[2][4096];
    __shared__ short Ps[4][16 * 72];

    const int t = threadIdx.x;
    const int w = t >> 6, l = t & 63, g = l >> 4, lr = l & 15;
    const int blk = blockIdx.x;
    const int qt = 15 - (blk >> 6);          // longest-first dispatch
    const int bh = blk & 63;
    const int b = bh >> 4, h = bh & 15;
    const short* Qg = Qw + ((long)bh << 16);
    const short* Kg = Kw + ((long)bh << 16);
    const short* Vg = Vt + ((long)bh << 16);

    bf16x8 qf[2];
    {
        const short* qr = Qg + (long)(qt * 64 + w * 16 + lr) * 64;
        qf[0] = *(const bf16x8*)(qr + g * 8);
        qf[1] = *(const bf16x8*)(qr + 32 + g * 8);
    }

    float rsum[4] = {0.f, 0.f, 0.f, 0.f};
    f32x4 o[4] = {};
    short* ps = &Ps[w][0];

    auto stage = [&](int d, int kt) {
        #pragma unroll
        for (int it = 0; it < 2; ++it) {
            int seg = (w << 1) + it;                 // 0..7
            int row = (seg << 3) + (l >> 3);         // 0..63
            int slot = (l & 7) ^ (row & 7);
            gload_lds16(Kg + ((long)((kt << 6) + row) << 6) + (slot << 3), &Kb[d][seg << 9]);
            gload_lds16(Vg + ((long)row << 10) + (kt << 6) + (slot << 3), &Vb[d][seg << 9]);
        }
    };

    stage(0, 0);
    __syncthreads();

    for (int kt = 0; kt <= qt; ++kt) {
        const int cur = kt & 1;
        if (kt < qt) stage(cur ^ 1, kt + 1);
        const bool diag = (kt == qt);

        // QK^T
        f32x4 s[4] = {};
        __builtin_amdgcn_s_setprio(1);
        #pragma unroll
        for (int kk = 0; kk < 2; ++kk)
            #pragma unroll
            for (int nt = 0; nt < 4; ++nt) {
                bf16x8 kf = *(const bf16x8*)&Kb[cur][((nt * 16 + lr) << 6) +
                            ((((kk << 2) + g) ^ (lr & 7)) << 3)];
                s[nt] = __builtin_amdgcn_mfma_f32_16x16x32_bf16(qf[kk], kf, s[nt], 0, 0, 0);
            }
        __builtin_amdgcn_s_setprio(0);
        if (diag) {
            #pragma unroll
            for (int nt = 0; nt < 4; ++nt)
                #pragma unroll
                for (int r = 0; r < 4; ++r)
                    if (nt * 16 + lr > w * 16 + g * 4 + r) s[nt][r] = -1e30f;
        }

        // exp2-direct P; accumulate per-lane partial row sums
        #pragma unroll
        for (int nt = 0; nt < 4; ++nt)
            #pragma unroll
            for (int r = 0; r < 4; ++r) {
                float p = exp2f(s[nt][r]);
                rsum[r] += p;
                ps[(g * 4 + r) * 72 + nt * 16 + lr] = f2bf(p);
            }

        asm volatile("s_waitcnt lgkmcnt(0)" ::: "memory");

        // PV
        __builtin_amdgcn_s_setprio(1);
        #pragma unroll
        for (int kk = 0; kk < 2; ++kk) {
            bf16x8 pf = *(const bf16x8*)&ps[lr * 72 + kk * 32 + g * 8];
            #pragma unroll
            for (int nt = 0; nt < 4; ++nt) {
                bf16x8 vf = *(const bf16x8*)&Vb[cur][((nt * 16 + lr) << 6) +
                            ((((kk << 2) + g) ^ (lr & 7)) << 3)];
                o[nt] = __builtin_amdgcn_mfma_f32_16x16x32_bf16(pf, vf, o[nt], 0, 0, 0);
            }
        }
        __builtin_amdgcn_s_setprio(0);
        __syncthreads();
    }

    // epilogue: one deferred sum reduction, normalize, write bf16 [B,S,D]
    float rinv[4];
    #pragma unroll
    for (int r = 0; r < 4; ++r) {
        float rs = rsum[r];
        rs += __shfl_xor(rs, 1, 64);
        rs += __shfl_xor(rs, 2, 64);
        rs += __shfl_xor(rs, 4, 64);
        rs += __shfl_xor(rs, 8, 64);
        rinv[r] = 1.0f / rs;
    }
    #pragma unroll
    for (int nt = 0; nt < 4; ++nt)
        #pragma unroll
        for (int r = 0; r < 4; ++r) {
            float val = o[nt][r] * rinv[r];
            int srow = qt * 64 + w * 16 + g * 4 + r;
            Aw[((long)(b * 1024 + srow) << 10) + h * 64 + nt * 16 + lr] = f2bf(val);
        }
}

// ---------------------------------------------------------------------------
// Kernel 3: output projection (m97 structure), XCD-bijective swizzle.
// ---------------------------------------------------------------------------
__global__ __launch_bounds__(256) void proj_gemm(
    const short* __restrict__ A,      // [4096][1024] bf16
    const short* __restrict__ Bt,     // [1024][1024] bf16 (N-major)
    const float* __restrict__ bias,   // [1024]
    float* __restrict__ out)
{
    __shared__ short As[128 * 64];
    __shared__ short Bs[128 * 64];

    const int t  = threadIdx.x;
    const int w  = t >> 6, l = t & 63;
    const int g  = l >> 4, lr = l & 15;
    const int swz = (blockIdx.x & 7) * 32 + (blockIdx.x >> 3);  // 256 blocks
    const int m0 = (swz & 31) * 128;
    const int n0 = (swz >> 5) * 128;
    const int wm = (w >> 1) * 64, wn = (w & 1) * 64;
    const int srow = l >> 3, sc = (l & 7) << 3;

    f32x4 acc[4][4] = {};

    for (int k0 = 0; k0 < 1024; k0 += 64) {
        #pragma unroll
        for (int it = 0; it < 4; ++it) {
            const int seg = w * 4 + it;
            const int row = seg * 8 + srow;
            gload_lds16(&A [(long)(m0 + row) * 1024 + k0 + sc], &As[seg * 512]);
            gload_lds16(&Bt[(long)(n0 + row) * 1024 + k0 + sc], &Bs[seg * 512]);
        }
        __syncthreads();
        #pragma unroll
        for (int kk = 0; kk < 64; kk += 32) {
            bf16x8 af[4], bfv[4];
            #pragma unroll
            for (int mi = 0; mi < 4; ++mi)
                af[mi] = *reinterpret_cast<const bf16x8*>(&As[(wm + mi * 16 + lr) * 64 + kk + g * 8]);
            #pragma unroll
            for (int ni = 0; ni < 4; ++ni)
                bfv[ni] = *reinterpret_cast<const bf16x8*>(&Bs[(wn + ni * 16 + lr) * 64 + kk + g * 8]);
            #pragma unroll
            for (int mi = 0; mi < 4; ++mi)
                #pragma unroll
                for (int ni = 0; ni < 4; ++ni)
                    acc[mi][ni] = __builtin_amdgcn_mfma_f32_16x16x32_bf16(
                        af[mi], bfv[ni], acc[mi][ni], 0, 0, 0);
        }
        __syncthreads();
    }

    #pragma unroll
    for (int mi = 0; mi < 4; ++mi)
        #pragma unroll
        for (int ni = 0; ni < 4; ++ni) {
            int n = n0 + wn + ni * 16 + lr;
            float bv = bias[n];
            #pragma unroll
            for (int r = 0; r < 4; ++r) {
                int m = m0 + wm + mi * 16 + g * 4 + r;
                out[m * 1024 + n] = acc[mi][ni][r] + bv;
            }
        }
}

// ---------------------------------------------------------------------------
// Workspace (40 MB): Hb/Aw(8MB) W1t(6MB) W2t(2MB) Qw(8MB) Kw(8MB) Vt(8MB)
// ---------------------------------------------------------------------------
extern "C" void kernel_launch(void* const* d_in, const int* in_sizes, int n_in,
                              void* d_out, int out_size, void* d_ws, size_t ws_size,
                              hipStream_t stream)
{
    const float* hs     = (const float*)d_in[0];
    const float* attn_w = (const float*)d_in[1];
    const float* attn_b = (const float*)d_in[2];
    const float* proj_w = (const float*)d_in[3];
    const float* proj_b = (const float*)d_in[4];
    float* out = (float*)d_out;

    short* Hb  = (short*)d_ws;             // 4096*1024
    short* W1t = Hb  + 4194304L;           // 3072*1024
    short* W2t = W1t + 3145728L;           // 1024*1024
    short* Qw  = W2t + 1048576L;
    short* Kw  = Qw  + 4194304L;
    short* Vt  = Kw  + 4194304L;
    short* Aw  = Hb;                       // alias: Hb dead after qkv_all

    prep<<<2048, 256, 0, stream>>>(hs, attn_w, proj_w, Hb, W1t, W2t);
    qkv_all<<<768, 256, 0, stream>>>(Hb, W1t, attn_b, Qw, Kw, Vt);
    attn<<<1024, 256, 0, stream>>>(Qw, Kw, Vt, Aw);
    proj_gemm<<<256, 256, 0, stream>>>(Aw, W2t, proj_b, out);
}